// Round 4
// baseline (9371.571 us; speedup 1.0000x reference)
//
#include <hip/hip_runtime.h>
#include <hip/hip_bf16.h>

// ---------------------------------------------------------------------------
// CFODE: bi-GRU encoder/decoder -> latent SDE (140 Euler steps, 3-layer MLP
// drift with tanh+LayerNorm) -> decoder head.
//
// Round 6: exchange-free SDE. Round-3 counters proved workspace stores write
// through to HBM (WRITE_SIZE pinned at ~127 MB = exchange volume) so every
// cohort barrier pays HBM ack latency x3 serial phases/step -> ~23 us/step
// floor. This version deletes the cohort entirely: one row per WG (128 WGs x
// 512 threads), each WG streams ALL MLP weights from the XCD-local L2 every
// step (bf16 1 MB/step, L2-resident, per-CU stream ~3-7 us/step) and does
// LayerNorm reductions intra-WG (shfl + LDS). Zero inter-WG communication,
// zero atomics, zero volatile. GRU + epilogue kernels unchanged (verified).
// ---------------------------------------------------------------------------

#define EPS    1e-5f
#define DT_    0.05f
#define SQDT_  0.22360680997371674f   // sqrt(0.05)
#define SIG_   0.5f

#define NB    128
#define NLH   64
#define NLP   8
#define NSTEP 140
#define NSUB  20

// ws layout (float offsets). Only WSH (GRU hidden) and YS (trajectory) used.
#define WSH_OFF   0           // [128 rows][4 which][128]     = 65536
#define YS_OFF    65536       // [128 rows][8 samples][257]   = 263168
#define SLOT_OFF  504832      // legacy barrier slots (zeroed, unused)

typedef __attribute__((ext_vector_type(8))) unsigned short ushort8;

__device__ __forceinline__ float bf2f(unsigned short u) {
  return __uint_as_float(((unsigned)u) << 16);
}
__device__ __forceinline__ float ldv(const void* p, int i, bool bf) {
  return bf ? bf2f(((const unsigned short*)p)[i]) : ((const float*)p)[i];
}
__device__ __forceinline__ void st_out(void* p, int i, float v, bool bf) {
  if (bf) ((__hip_bfloat16*)p)[i] = __float2bfloat16(v);
  else    ((float*)p)[i] = v;
}
__device__ __forceinline__ float sigm(float x) { return 1.f / (1.f + expf(-x)); }

// ---------------------------------------------------------------------------
// GRU: 384 threads, thread j owns gate-row j (0..127 r, 128..255 z, 256..383 n)
// ---------------------------------------------------------------------------
template<int INSZ, int TSTEPS>
__device__ void gru_run(const float* xs, int rev,
                        const void* Wih, const void* Whh,
                        const void* bih, const void* bhh,
                        bool bf, float* hout,
                        float* h0, float* h1, float* rz)
{
  const int j = threadIdx.x;
  float whh[128];
  float wih[INSZ];
  if (bf) {
    const unsigned short* wp = (const unsigned short*)Whh;
    #pragma unroll
    for (int k = 0; k < 128; ++k) whh[k] = bf2f(wp[j*128 + k]);
    const unsigned short* ip = (const unsigned short*)Wih;
    #pragma unroll
    for (int c = 0; c < INSZ; ++c) wih[c] = bf2f(ip[j*INSZ + c]);
  } else {
    const float* wp = (const float*)Whh;
    #pragma unroll
    for (int k = 0; k < 128; ++k) whh[k] = wp[j*128 + k];
    const float* ip = (const float*)Wih;
    #pragma unroll
    for (int c = 0; c < INSZ; ++c) wih[c] = ip[j*INSZ + c];
  }
  const float bi = ldv(bih, j, bf);
  const float bh = ldv(bhh, j, bf);
  if (j < 128) h0[j] = 0.f;
  __syncthreads();

  #pragma unroll 1
  for (int it = 0; it < TSTEPS; ++it) {
    const float* hc = (it & 1) ? h1 : h0;
    float*       hn = (it & 1) ? h0 : h1;
    const int t = rev ? (TSTEPS - 1 - it) : it;
    float gh = bh;
    const float4* h4 = (const float4*)hc;
    #pragma unroll
    for (int k4 = 0; k4 < 32; ++k4) {
      const float4 hv = h4[k4];
      gh += whh[k4*4+0]*hv.x + whh[k4*4+1]*hv.y + whh[k4*4+2]*hv.z + whh[k4*4+3]*hv.w;
    }
    float gi = bi;
    #pragma unroll
    for (int c = 0; c < INSZ; ++c) gi += wih[c] * xs[t*INSZ + c];
    if (j < 256) rz[j] = sigm(gi + gh);      // r (0..127), z (128..255)
    __syncthreads();
    if (j >= 256) {                           // n-threads also do the h update
      const int i = j - 256;
      const float n = tanhf(gi + rz[i]*gh);   // inn + r*hn (biases kept separate)
      const float z = rz[128 + i];
      hn[i] = (1.f - z)*n + z*hc[i];
    }
    __syncthreads();
  }
  const float* hf = (TSTEPS & 1) ? h1 : h0;
  if (j < 128) hout[j] = hf[j];
}

__global__ __launch_bounds__(384)
void k_gru_enc(const void* cov, const void* trh, const void* outh,
               const void* Wf, const void* Uf, const void* bf_, const void* cf_,
               const void* Wb, const void* Ub, const void* bb_, const void* cb_,
               float* ws, const void* lnvw)
{
  __shared__ __align__(16) float xs[NLH*28];
  __shared__ __align__(16) float h0[128], h1[128];
  __shared__ float rz[256];
  __shared__ float sm_[28], ss_[28];
  const bool bf = (((const unsigned*)lnvw)[0] != 0x3F800000u);
  const int bid = blockIdx.x;
  const int row = bid >> 1, back = bid & 1;
  const int tid = threadIdx.x;

  if (bid == 0) {  // legacy slot zeroing (region unused this round; harmless)
    unsigned* slots = (unsigned*)(ws + SLOT_OFF);
    for (int e = tid; e < 4096; e += 384) slots[e] = 0u;
  }
  if (tid < 28) {  // per-feature mean/std over time (population std)
    const void* src; int w; int f2;
    if (tid < 16)      { src = cov;  w = 16; f2 = tid; }
    else if (tid < 24) { src = trh;  w = 8;  f2 = tid - 16; }
    else               { src = outh; w = 4;  f2 = tid - 24; }
    float s1 = 0.f, s2 = 0.f;
    for (int t = 0; t < NLH; ++t) {
      const float v = ldv(src, (row*NLH + t)*w + f2, bf);
      s1 += v; s2 += v*v;
    }
    const float m = s1 / NLH;
    const float var = s2 / NLH - m*m;
    sm_[tid] = m;
    ss_[tid] = sqrtf(fmaxf(var, 0.f)) + EPS;
  }
  __syncthreads();
  for (int e = tid; e < NLH*28; e += 384) {  // enc_in = [ch(16), th(8), oh(4)]
    const int t = e / 28, f2 = e % 28;
    const void* src; int w; int ff;
    if (f2 < 16)      { src = cov;  w = 16; ff = f2; }
    else if (f2 < 24) { src = trh;  w = 8;  ff = f2 - 16; }
    else              { src = outh; w = 4;  ff = f2 - 24; }
    const float v = ldv(src, (row*NLH + t)*w + ff, bf);
    xs[e] = (v - sm_[f2]) / ss_[f2];
  }
  __syncthreads();
  float* hout = ws + WSH_OFF + (row*4 + back)*128;
  if (back == 0) gru_run<28, NLH>(xs, 0, Wf, Uf, bf_, cf_, bf, hout, h0, h1, rz);
  else           gru_run<28, NLH>(xs, 1, Wb, Ub, bb_, cb_, bf, hout, h0, h1, rz);
}

__global__ __launch_bounds__(384)
void k_gru_dec(const void* trh, const void* trt,
               const void* Wf, const void* Uf, const void* bf_, const void* cf_,
               const void* Wb, const void* Ub, const void* bb_, const void* cb_,
               float* ws, const void* lnvw)
{
  __shared__ __align__(16) float xs[NLP*8];
  __shared__ __align__(16) float h0[128], h1[128];
  __shared__ float rz[256];
  __shared__ float sm_[8], ss_[8];
  const bool bf = (((const unsigned*)lnvw)[0] != 0x3F800000u);
  const int row = blockIdx.x >> 1, back = blockIdx.x & 1;
  const int tid = threadIdx.x;
  if (tid < 8) {  // treatment stats come from treatment_history
    float s1 = 0.f, s2 = 0.f;
    for (int t = 0; t < NLH; ++t) {
      const float v = ldv(trh, (row*NLH + t)*8 + tid, bf);
      s1 += v; s2 += v*v;
    }
    const float m = s1 / NLH;
    const float var = s2 / NLH - m*m;
    sm_[tid] = m;
    ss_[tid] = sqrtf(fmaxf(var, 0.f)) + EPS;
  }
  __syncthreads();
  for (int e = tid; e < NLP*8; e += 384) {
    const int t = e >> 3, f2 = e & 7;
    const float v = ldv(trt, (row*NLP + t)*8 + f2, bf);
    xs[e] = (v - sm_[f2]) / ss_[f2];
  }
  __syncthreads();
  float* hout = ws + WSH_OFF + (row*4 + 2 + back)*128;
  if (back == 0) gru_run<8, NLP>(xs, 0, Wf, Uf, bf_, cf_, bf, hout, h0, h1, rz);
  else           gru_run<8, NLP>(xs, 1, Wb, Ub, bb_, cb_, bf, hout, h0, h1, rz);
}

// ---------------------------------------------------------------------------
// SDE kernel: 1 row per WG, 512 threads, weights streamed from L2 each step.
// ---------------------------------------------------------------------------
// Dot of one weight row (NCHUNK*8 elems) with the LDS input vector.
// 4 accumulators break the FMA dependency chain; LDS reads are same-address
// broadcasts (conflict-free).
template<int NCHUNK>
__device__ __forceinline__ float dotrow_bf(const unsigned short* wrow,
                                           const float4* in4)
{
  float a0 = 0.f, a1 = 0.f, a2 = 0.f, a3 = 0.f;
  #pragma unroll
  for (int kc = 0; kc < NCHUNK; kc += 4) {
    #pragma unroll
    for (int q = 0; q < 4; ++q) {
      const ushort8 w8 = *(const ushort8*)(wrow + (kc + q)*8);
      const float4 xa = in4[2*(kc + q)];
      const float4 xb = in4[2*(kc + q) + 1];
      float p = bf2f(w8[0])*xa.x + bf2f(w8[1])*xa.y
              + bf2f(w8[2])*xa.z + bf2f(w8[3])*xa.w
              + bf2f(w8[4])*xb.x + bf2f(w8[5])*xb.y
              + bf2f(w8[6])*xb.z + bf2f(w8[7])*xb.w;
      if (q == 0) a0 += p; else if (q == 1) a1 += p;
      else if (q == 2) a2 += p; else a3 += p;
    }
  }
  return (a0 + a1) + (a2 + a3);
}
template<int NCHUNK>
__device__ __forceinline__ float dotrow_f32(const float* wrow,
                                            const float4* in4)
{
  float a0 = 0.f, a1 = 0.f, a2 = 0.f, a3 = 0.f;
  #pragma unroll
  for (int kc = 0; kc < NCHUNK; kc += 4) {
    #pragma unroll
    for (int q = 0; q < 4; ++q) {
      const float4 w0 = *(const float4*)(wrow + (kc + q)*8);
      const float4 w1 = *(const float4*)(wrow + (kc + q)*8 + 4);
      const float4 xa = in4[2*(kc + q)];
      const float4 xb = in4[2*(kc + q) + 1];
      float p = w0.x*xa.x + w0.y*xa.y + w0.z*xa.z + w0.w*xa.w
              + w1.x*xb.x + w1.y*xb.y + w1.z*xb.z + w1.w*xb.w;
      if (q == 0) a0 += p; else if (q == 1) a1 += p;
      else if (q == 2) a2 += p; else a3 += p;
    }
  }
  return (a0 + a1) + (a2 + a3);
}

__device__ __forceinline__ void wave_red2(float& s1, float& s2) {
  #pragma unroll
  for (int off = 32; off >= 1; off >>= 1) {
    s1 += __shfl_xor(s1, off, 64);
    s2 += __shfl_xor(s2, off, 64);
  }
}

__global__ __launch_bounds__(512)
void k_sde(float* ws,
           const void* W0, const void* b0, const void* g0, const void* be0,
           const void* W1, const void* b1, const void* g1, const void* be1,
           const void* W2, const void* b2, const void* g2, const void* be2,
           const void* noise, const void* lnvw)
{
  __shared__ __align__(16) float xs[256];   // current latent state y
  __shared__ __align__(16) float a1[512];   // layer-1 activation
  __shared__ __align__(16) float a2[512];   // layer-2 act / layer-3 out (256)
  __shared__ __align__(16) float ps[512];   // layer-3 K-split partials
  __shared__ float red[16];                 // per-wave (s1,s2) partials
  __shared__ float lacc_s;

  const bool bf = (((const unsigned*)lnvw)[0] != 0x3F800000u);
  const int row = blockIdx.x;               // 128 rows, one per WG
  const int t   = threadIdx.x;              // 512 threads
  const int lane = t & 63, wv = t >> 6;     // 8 waves

  // Per-thread layer params (col t for A,B; col t&255 for C).
  const float bAv  = ldv(b0, t, bf), gAv = ldv(g0, t, bf), beAv = ldv(be0, t, bf);
  const float bBv  = ldv(b1, t, bf), gBv = ldv(g1, t, bf), beBv = ldv(be1, t, bf);
  const int   cC   = t & 255, khC = t >> 8;
  float bCv = 0.f, gCv = 0.f, beCv = 0.f;
  if (t < 256) { bCv = ldv(b2, t, bf); gCv = ldv(g2, t, bf); beCv = ldv(be2, t, bf); }

  const unsigned short* W0b = (const unsigned short*)W0;
  const unsigned short* W1b = (const unsigned short*)W1;
  const unsigned short* W2b = (const unsigned short*)W2;
  const float* W0f = (const float*)W0;
  const float* W1f = (const float*)W1;
  const float* W2f = (const float*)W2;

  // x0 = [0.5*(enc_f+enc_b), 0.5*(dec_f+dec_b)]
  const float* wsh = ws + WSH_OFF;
  if (t < 256) {
    float v;
    if (t < 128) v = 0.5f*(wsh[(row*4 + 0)*128 + t]        + wsh[(row*4 + 1)*128 + t]);
    else         v = 0.5f*(wsh[(row*4 + 2)*128 + (t-128)]  + wsh[(row*4 + 3)*128 + (t-128)]);
    xs[t] = v;
  }
  if (t == 0) lacc_s = 0.f;
  __syncthreads();
  float* ysw = ws + YS_OFF;
  if (t < 257) ysw[(row*8 + 0)*257 + t] = (t < 256) ? xs[t] : 0.f;  // sample 0

  #pragma unroll 1
  for (int s = 0; s < NSTEP; ++s) {
    // ---- layer A: 512 cols x K=256 ----------------------------------------
    float acc = bf ? dotrow_bf<32>(W0b + t*256, (const float4*)xs)
                   : dotrow_f32<32>(W0f + t*256, (const float4*)xs);
    float v = tanhf(acc + bAv);
    float s1 = v, s2 = v*v;
    wave_red2(s1, s2);
    if (lane == 0) { red[wv*2] = s1; red[wv*2 + 1] = s2; }
    __syncthreads();
    {
      float t1 = 0.f, t2 = 0.f;
      #pragma unroll
      for (int q = 0; q < 8; ++q) { t1 += red[q*2]; t2 += red[q*2 + 1]; }
      const float m = t1/512.f, var = t2/512.f - m*m, rs = rsqrtf(var + EPS);
      a1[t] = (v - m)*rs*gAv + beAv;
    }
    __syncthreads();
    // ---- layer B: 512 cols x K=512 ----------------------------------------
    acc = bf ? dotrow_bf<64>(W1b + t*512, (const float4*)a1)
             : dotrow_f32<64>(W1f + t*512, (const float4*)a1);
    v = tanhf(acc + bBv);
    s1 = v; s2 = v*v;
    wave_red2(s1, s2);
    if (lane == 0) { red[wv*2] = s1; red[wv*2 + 1] = s2; }
    __syncthreads();
    {
      float t1 = 0.f, t2 = 0.f;
      #pragma unroll
      for (int q = 0; q < 8; ++q) { t1 += red[q*2]; t2 += red[q*2 + 1]; }
      const float m = t1/512.f, var = t2/512.f - m*m, rs = rsqrtf(var + EPS);
      a2[t] = (v - m)*rs*gBv + beBv;
    }
    __syncthreads();
    // ---- layer C: 256 cols x K=512, K split across thread halves ----------
    acc = bf ? dotrow_bf<32>(W2b + cC*512 + khC*256, (const float4*)a2 + khC*64)
             : dotrow_f32<32>(W2f + cC*512 + khC*256, (const float4*)a2 + khC*64);
    ps[t] = acc;
    __syncthreads();
    if (t < 256) {
      v = tanhf(ps[t] + ps[t + 256] + bCv);
      s1 = v; s2 = v*v;
    } else { v = 0.f; s1 = 0.f; s2 = 0.f; }
    wave_red2(s1, s2);
    if (lane == 0) { red[wv*2] = s1; red[wv*2 + 1] = s2; }
    __syncthreads();
    {
      const float t1 = red[0] + red[2] + red[4] + red[6];
      const float t2 = red[1] + red[3] + red[5] + red[7];
      const float m = t1/256.f, var = t2/256.f - m*m, rs = rsqrtf(var + EPS);
      if (t < 256) a2[t] = (v - m)*rs*gCv + beCv;   // drift f
    }
    __syncthreads();
    // ---- Euler step + flq --------------------------------------------------
    float u2 = 0.f, ynew = 0.f;
    if (t < 256) {
      const float nz  = ldv(noise, ((s*NB) + row)*256 + t, bf);
      const float ysv = xs[t];
      const float fv  = a2[t];
      const float uu  = fv + ysv;       // u = 2*(f+ys); scale folded into lacc
      u2   = uu*uu;
      ynew = ysv + fv*DT_ + SIG_*SQDT_*nz;
    }
    s1 = u2; s2 = 0.f;
    wave_red2(s1, s2);
    if (lane == 0) red[wv*2] = s1;
    if (t < 256) xs[t] = ynew;
    __syncthreads();
    if (t == 0) lacc_s += 2.f*(red[0] + red[2] + red[4] + red[6])*DT_;
    __syncthreads();
    if (((s + 1) % NSUB) == 0) {
      const int smp = (s + 1)/NSUB;
      if (t < 257) ysw[(row*8 + smp)*257 + t] = (t < 256) ? xs[t] : lacc_s;
    }
  }
}

// ---------------------------------------------------------------------------
// Epilogue: decoder head + output packing (mu | var | logqp)
// ---------------------------------------------------------------------------
__global__ __launch_bounds__(128)
void k_epi(const float* ws, const void* outh,
           const void* outW, const void* outB,
           const void* lvw, const void* lvb,
           void* d_out)
{
  __shared__ __align__(16) float ysl[8*257];
  __shared__ __align__(16) float ow[8*128];
  __shared__ float dout[64];
  __shared__ float om4[4], os4[4], vmv[4], vrs[4], ob[8], lw[4], lb[4];
  const bool bf = (((const unsigned*)lvw)[0] != 0x3F800000u);
  const int row = blockIdx.x, tid = threadIdx.x;
  const float* ysw = ws + YS_OFF + row*(8*257);
  for (int e = tid; e < 8*257; e += 128) ysl[e] = ysw[e];
  for (int e = tid; e < 1024; e += 128)  ow[e]  = ldv(outW, e, bf);
  if (tid < 8) ob[tid] = ldv(outB, tid, bf);
  if (tid < 4) { lw[tid] = ldv(lvw, tid, bf); lb[tid] = ldv(lvb, tid, bf); }
  if (tid < 4) {  // om / os_ from outcome_history
    float s1 = 0.f, s2 = 0.f;
    for (int t = 0; t < NLH; ++t) {
      const float v = ldv(outh, (row*NLH + t)*4 + tid, bf);
      s1 += v; s2 += v*v;
    }
    const float m = s1 / NLH;
    const float var = s2 / NLH - m*m;
    om4[tid] = m;
    os4[tid] = sqrtf(fmaxf(var, 0.f)) + EPS;   // already includes +EPS
  }
  __syncthreads();
  if (tid < 64) {
    const int smp = tid >> 3, o = tid & 7;
    float a = ob[o];
    #pragma unroll
    for (int k = 0; k < 128; ++k) a += ysl[smp*257 + k]*ow[o*128 + k];
    dout[smp*8 + o] = a;
  }
  __syncthreads();
  if (tid < 4) {  // var_o mean/var over the 8 samples
    float s1 = 0.f, s2 = 0.f;
    #pragma unroll
    for (int smp = 0; smp < 8; ++smp) { const float v = dout[smp*8 + 4 + tid]; s1 += v; s2 += v*v; }
    const float m = s1 / 8.f;
    const float var = s2 / 8.f - m*m;
    vmv[tid] = m;
    vrs[tid] = rsqrtf(var + EPS);
  }
  __syncthreads();
  if (tid < 32) {
    const int smp = tid >> 2, j = tid & 3;
    const float mu = dout[smp*8 + j]*os4[j] + om4[j];
    st_out(d_out, (row*8 + smp)*4 + j, mu, bf);
    const float vo = dout[smp*8 + 4 + j];
    const float vr = sigm((vo - vmv[j])*vrs[j]*lw[j] + lb[j]);
    st_out(d_out, 4096 + (row*8 + smp)*4 + j, vr, bf);
  }
  for (int e = tid; e < 129*8; e += 128) {
    const int j = e >> 3, smp = e & 7;
    st_out(d_out, 8192 + (row*129 + j)*8 + smp, ysl[smp*257 + 128 + j], bf);
  }
}

// ---------------------------------------------------------------------------
extern "C" void kernel_launch(void* const* d_in, const int* in_sizes, int n_in,
                              void* d_out, int out_size, void* d_ws, size_t ws_size,
                              hipStream_t stream) {
  (void)in_sizes; (void)n_in; (void)out_size; (void)ws_size;
  float* ws = (float*)d_ws;
  const void* lnvw = d_in[35];

  k_gru_enc<<<256, 384, 0, stream>>>(
      d_in[0], d_in[1], d_in[2],
      d_in[5], d_in[6], d_in[7], d_in[8],
      d_in[9], d_in[10], d_in[11], d_in[12],
      ws, lnvw);
  k_gru_dec<<<256, 384, 0, stream>>>(
      d_in[1], d_in[3],
      d_in[13], d_in[14], d_in[15], d_in[16],
      d_in[17], d_in[18], d_in[19], d_in[20],
      ws, lnvw);
  k_sde<<<128, 512, 0, stream>>>(
      ws,
      d_in[21], d_in[22], d_in[23], d_in[24],
      d_in[25], d_in[26], d_in[27], d_in[28],
      d_in[29], d_in[30], d_in[31], d_in[32],
      d_in[37], lnvw);
  k_epi<<<128, 128, 0, stream>>>(
      (const float*)d_ws, d_in[2],
      d_in[33], d_in[34], d_in[35], d_in[36],
      d_out);
}

// Round 5
// 3618.521 us; speedup vs baseline: 2.5899x; 2.5899x over previous
//
#include <hip/hip_runtime.h>
#include <hip/hip_bf16.h>

// ---------------------------------------------------------------------------
// CFODE: bi-GRU encoder/decoder -> latent SDE (140 Euler steps, 3-layer MLP
// drift with tanh+LayerNorm) -> decoder head.
//
// Round 7: exchange-free SDE (one row per WG, weights streamed from L2 each
// step) with the round-6 failure modes fixed:
//  (a) spills: round-6 WRITE_SIZE=860MB was scratch writeback (full-unroll
//      hoisted ~64 loads/thread). Now each thread holds ONE batch of weight
//      chunks (<=8 x 16B) and the batch loop is unroll-1 -> ~60 VGPR.
//  (b) coalescing: round-6 read 16B/lane at 512B lane stride (25% segment
//      efficiency). Now an 8-lane group covers 128B of one weight row per
//      instruction (100% segment consumption, 1KB/instr/wave); row dot is
//      folded with 3 shfl_xor inside the group.
// Zero inter-WG communication, zero atomics. GRU + epilogue unchanged.
// ---------------------------------------------------------------------------

#define EPS    1e-5f
#define DT_    0.05f
#define SQDT_  0.22360680997371674f   // sqrt(0.05)
#define SIG_   0.5f

#define NB    128
#define NLH   64
#define NLP   8
#define NSTEP 140
#define NSUB  20

// ws layout (float offsets). Only WSH (GRU hidden) and YS (trajectory) used.
#define WSH_OFF   0           // [128 rows][4 which][128]     = 65536
#define YS_OFF    65536       // [128 rows][8 samples][257]   = 263168
#define SLOT_OFF  504832      // legacy barrier slots (zeroed, unused)

typedef __attribute__((ext_vector_type(8))) unsigned short ushort8;

__device__ __forceinline__ float bf2f(unsigned short u) {
  return __uint_as_float(((unsigned)u) << 16);
}
__device__ __forceinline__ float ldv(const void* p, int i, bool bf) {
  return bf ? bf2f(((const unsigned short*)p)[i]) : ((const float*)p)[i];
}
__device__ __forceinline__ void st_out(void* p, int i, float v, bool bf) {
  if (bf) ((__hip_bfloat16*)p)[i] = __float2bfloat16(v);
  else    ((float*)p)[i] = v;
}
__device__ __forceinline__ float sigm(float x) { return 1.f / (1.f + expf(-x)); }

// ---------------------------------------------------------------------------
// GRU: 384 threads, thread j owns gate-row j (0..127 r, 128..255 z, 256..383 n)
// ---------------------------------------------------------------------------
template<int INSZ, int TSTEPS>
__device__ void gru_run(const float* xs, int rev,
                        const void* Wih, const void* Whh,
                        const void* bih, const void* bhh,
                        bool bf, float* hout,
                        float* h0, float* h1, float* rz)
{
  const int j = threadIdx.x;
  float whh[128];
  float wih[INSZ];
  if (bf) {
    const unsigned short* wp = (const unsigned short*)Whh;
    #pragma unroll
    for (int k = 0; k < 128; ++k) whh[k] = bf2f(wp[j*128 + k]);
    const unsigned short* ip = (const unsigned short*)Wih;
    #pragma unroll
    for (int c = 0; c < INSZ; ++c) wih[c] = bf2f(ip[j*INSZ + c]);
  } else {
    const float* wp = (const float*)Whh;
    #pragma unroll
    for (int k = 0; k < 128; ++k) whh[k] = wp[j*128 + k];
    const float* ip = (const float*)Wih;
    #pragma unroll
    for (int c = 0; c < INSZ; ++c) wih[c] = ip[j*INSZ + c];
  }
  const float bi = ldv(bih, j, bf);
  const float bh = ldv(bhh, j, bf);
  if (j < 128) h0[j] = 0.f;
  __syncthreads();

  #pragma unroll 1
  for (int it = 0; it < TSTEPS; ++it) {
    const float* hc = (it & 1) ? h1 : h0;
    float*       hn = (it & 1) ? h0 : h1;
    const int t = rev ? (TSTEPS - 1 - it) : it;
    float gh = bh;
    const float4* h4 = (const float4*)hc;
    #pragma unroll
    for (int k4 = 0; k4 < 32; ++k4) {
      const float4 hv = h4[k4];
      gh += whh[k4*4+0]*hv.x + whh[k4*4+1]*hv.y + whh[k4*4+2]*hv.z + whh[k4*4+3]*hv.w;
    }
    float gi = bi;
    #pragma unroll
    for (int c = 0; c < INSZ; ++c) gi += wih[c] * xs[t*INSZ + c];
    if (j < 256) rz[j] = sigm(gi + gh);      // r (0..127), z (128..255)
    __syncthreads();
    if (j >= 256) {                           // n-threads also do the h update
      const int i = j - 256;
      const float n = tanhf(gi + rz[i]*gh);   // inn + r*hn (biases kept separate)
      const float z = rz[128 + i];
      hn[i] = (1.f - z)*n + z*hc[i];
    }
    __syncthreads();
  }
  const float* hf = (TSTEPS & 1) ? h1 : h0;
  if (j < 128) hout[j] = hf[j];
}

__global__ __launch_bounds__(384)
void k_gru_enc(const void* cov, const void* trh, const void* outh,
               const void* Wf, const void* Uf, const void* bf_, const void* cf_,
               const void* Wb, const void* Ub, const void* bb_, const void* cb_,
               float* ws, const void* lnvw)
{
  __shared__ __align__(16) float xs[NLH*28];
  __shared__ __align__(16) float h0[128], h1[128];
  __shared__ float rz[256];
  __shared__ float sm_[28], ss_[28];
  const bool bf = (((const unsigned*)lnvw)[0] != 0x3F800000u);
  const int bid = blockIdx.x;
  const int row = bid >> 1, back = bid & 1;
  const int tid = threadIdx.x;

  if (bid == 0) {  // legacy slot zeroing (region unused this round; harmless)
    unsigned* slots = (unsigned*)(ws + SLOT_OFF);
    for (int e = tid; e < 4096; e += 384) slots[e] = 0u;
  }
  if (tid < 28) {  // per-feature mean/std over time (population std)
    const void* src; int w; int f2;
    if (tid < 16)      { src = cov;  w = 16; f2 = tid; }
    else if (tid < 24) { src = trh;  w = 8;  f2 = tid - 16; }
    else               { src = outh; w = 4;  f2 = tid - 24; }
    float s1 = 0.f, s2 = 0.f;
    for (int t = 0; t < NLH; ++t) {
      const float v = ldv(src, (row*NLH + t)*w + f2, bf);
      s1 += v; s2 += v*v;
    }
    const float m = s1 / NLH;
    const float var = s2 / NLH - m*m;
    sm_[tid] = m;
    ss_[tid] = sqrtf(fmaxf(var, 0.f)) + EPS;
  }
  __syncthreads();
  for (int e = tid; e < NLH*28; e += 384) {  // enc_in = [ch(16), th(8), oh(4)]
    const int t = e / 28, f2 = e % 28;
    const void* src; int w; int ff;
    if (f2 < 16)      { src = cov;  w = 16; ff = f2; }
    else if (f2 < 24) { src = trh;  w = 8;  ff = f2 - 16; }
    else              { src = outh; w = 4;  ff = f2 - 24; }
    const float v = ldv(src, (row*NLH + t)*w + ff, bf);
    xs[e] = (v - sm_[f2]) / ss_[f2];
  }
  __syncthreads();
  float* hout = ws + WSH_OFF + (row*4 + back)*128;
  if (back == 0) gru_run<28, NLH>(xs, 0, Wf, Uf, bf_, cf_, bf, hout, h0, h1, rz);
  else           gru_run<28, NLH>(xs, 1, Wb, Ub, bb_, cb_, bf, hout, h0, h1, rz);
}

__global__ __launch_bounds__(384)
void k_gru_dec(const void* trh, const void* trt,
               const void* Wf, const void* Uf, const void* bf_, const void* cf_,
               const void* Wb, const void* Ub, const void* bb_, const void* cb_,
               float* ws, const void* lnvw)
{
  __shared__ __align__(16) float xs[NLP*8];
  __shared__ __align__(16) float h0[128], h1[128];
  __shared__ float rz[256];
  __shared__ float sm_[8], ss_[8];
  const bool bf = (((const unsigned*)lnvw)[0] != 0x3F800000u);
  const int row = blockIdx.x >> 1, back = blockIdx.x & 1;
  const int tid = threadIdx.x;
  if (tid < 8) {  // treatment stats come from treatment_history
    float s1 = 0.f, s2 = 0.f;
    for (int t = 0; t < NLH; ++t) {
      const float v = ldv(trh, (row*NLH + t)*8 + tid, bf);
      s1 += v; s2 += v*v;
    }
    const float m = s1 / NLH;
    const float var = s2 / NLH - m*m;
    sm_[tid] = m;
    ss_[tid] = sqrtf(fmaxf(var, 0.f)) + EPS;
  }
  __syncthreads();
  for (int e = tid; e < NLP*8; e += 384) {
    const int t = e >> 3, f2 = e & 7;
    const float v = ldv(trt, (row*NLP + t)*8 + f2, bf);
    xs[e] = (v - sm_[f2]) / ss_[f2];
  }
  __syncthreads();
  float* hout = ws + WSH_OFF + (row*4 + 2 + back)*128;
  if (back == 0) gru_run<8, NLP>(xs, 0, Wf, Uf, bf_, cf_, bf, hout, h0, h1, rz);
  else           gru_run<8, NLP>(xs, 1, Wb, Ub, bb_, cb_, bf, hout, h0, h1, rz);
}

// ---------------------------------------------------------------------------
// SDE kernel: 1 row per WG, 512 threads (8 waves), weights streamed from L2.
// Dot scheme: lane = (g = lane>>3 row-group, ks = lane&7 k-slot). An 8-lane
// group owns one output row; per iteration the group reads 128B of the row
// (lane-consecutive 16B chunks -> 100% segment utilization), input vector
// chunk comes from LDS (same address across groups -> broadcast). Row dot is
// folded with 3 intra-group shfl_xor. LayerNorm is intra-WG.
// ---------------------------------------------------------------------------
template<int N, int K>
__device__ __forceinline__ void mv_layer(
    const void* W, bool bf, const float* in, float* out,
    const float* bias, const float* gamma, const float* beta,
    float* red, int t, int lane, int wv, int g, int ks)
{
  constexpr int RPW = N/8;     // rows per wave
  constexpr int NBT = RPW/8;   // 8-row batches per wave
  constexpr int KI  = K/64;    // 128B chunks per row
  float ws1 = 0.f, ws2 = 0.f;
  #pragma unroll 1
  for (int b = 0; b < NBT; ++b) {
    const int row = wv*RPW + b*8 + g;
    float a0 = 0.f, a1 = 0.f;
    if (bf) {
      const unsigned short* wr = (const unsigned short*)W + row*K + ks*8;
      #pragma unroll
      for (int kt = 0; kt < KI; ++kt) {
        const ushort8 w8 = *(const ushort8*)(wr + kt*64);
        const float4 xa = *(const float4*)(in + kt*64 + ks*8);
        const float4 xb = *(const float4*)(in + kt*64 + ks*8 + 4);
        a0 += bf2f(w8[0])*xa.x + bf2f(w8[1])*xa.y
            + bf2f(w8[2])*xa.z + bf2f(w8[3])*xa.w;
        a1 += bf2f(w8[4])*xb.x + bf2f(w8[5])*xb.y
            + bf2f(w8[6])*xb.z + bf2f(w8[7])*xb.w;
      }
    } else {
      const float* wr = (const float*)W + row*K + ks*8;
      #pragma unroll
      for (int kt = 0; kt < KI; ++kt) {
        const float4 w0 = *(const float4*)(wr + kt*64);
        const float4 w1 = *(const float4*)(wr + kt*64 + 4);
        const float4 xa = *(const float4*)(in + kt*64 + ks*8);
        const float4 xb = *(const float4*)(in + kt*64 + ks*8 + 4);
        a0 += w0.x*xa.x + w0.y*xa.y + w0.z*xa.z + w0.w*xa.w;
        a1 += w1.x*xb.x + w1.y*xb.y + w1.z*xb.z + w1.w*xb.w;
      }
    }
    float acc = a0 + a1;
    acc += __shfl_xor(acc, 1, 64);   // fold the 8 k-slots of this row
    acc += __shfl_xor(acc, 2, 64);
    acc += __shfl_xor(acc, 4, 64);
    const float v = tanhf(acc + bias[row]);
    if (ks == 0) { out[row] = v; ws1 += v; ws2 += v*v; }
  }
  #pragma unroll
  for (int off = 32; off >= 1; off >>= 1) {   // wave total (non-ks0 lanes = 0)
    ws1 += __shfl_xor(ws1, off, 64);
    ws2 += __shfl_xor(ws2, off, 64);
  }
  if (lane == 0) { red[wv*2] = ws1; red[wv*2 + 1] = ws2; }
  __syncthreads();
  float t1 = 0.f, t2 = 0.f;
  #pragma unroll
  for (int q = 0; q < 8; ++q) { t1 += red[q*2]; t2 += red[q*2 + 1]; }
  const float m = t1/(float)N, var = t2/(float)N - m*m, rs = rsqrtf(var + EPS);
  if (t < N) out[t] = (out[t] - m)*rs*gamma[t] + beta[t];
  __syncthreads();
}

__global__ __launch_bounds__(512)
void k_sde(float* ws,
           const void* W0, const void* b0, const void* g0, const void* be0,
           const void* W1, const void* b1, const void* g1, const void* be1,
           const void* W2, const void* b2, const void* g2, const void* be2,
           const void* noise, const void* lnvw)
{
  __shared__ __align__(16) float xs[256];    // latent state y
  __shared__ __align__(16) float act1[512];  // layer-A out
  __shared__ __align__(16) float act2[512];  // layer-B out
  __shared__ __align__(16) float fC[256];    // layer-C out (drift f)
  __shared__ float prm[3840];                // bA gA beA bB gB beB bC gC beC
  __shared__ float red[16];
  __shared__ float lacc_s;

  const bool bf = (((const unsigned*)lnvw)[0] != 0x3F800000u);
  const int row = blockIdx.x;                // 128 rows, one per WG
  const int t = threadIdx.x;
  const int lane = t & 63, wv = t >> 6;
  const int g = lane >> 3, ks = lane & 7;

  float* bA = prm;        float* gA = prm +  512; float* beA = prm + 1024;
  float* bB = prm + 1536; float* gB = prm + 2048; float* beB = prm + 2560;
  float* bC = prm + 3072; float* gC = prm + 3328; float* beC = prm + 3584;
  bA[t] = ldv(b0, t, bf); gA[t] = ldv(g0, t, bf); beA[t] = ldv(be0, t, bf);
  bB[t] = ldv(b1, t, bf); gB[t] = ldv(g1, t, bf); beB[t] = ldv(be1, t, bf);
  if (t < 256) { bC[t] = ldv(b2, t, bf); gC[t] = ldv(g2, t, bf); beC[t] = ldv(be2, t, bf); }

  // x0 = [0.5*(enc_f+enc_b), 0.5*(dec_f+dec_b)]
  const float* wsh = ws + WSH_OFF;
  if (t < 256) {
    float v;
    if (t < 128) v = 0.5f*(wsh[(row*4 + 0)*128 + t]       + wsh[(row*4 + 1)*128 + t]);
    else         v = 0.5f*(wsh[(row*4 + 2)*128 + (t-128)] + wsh[(row*4 + 3)*128 + (t-128)]);
    xs[t] = v;
  }
  if (t == 0) lacc_s = 0.f;
  __syncthreads();
  float* ysw = ws + YS_OFF;
  if (t < 257) ysw[(row*8 + 0)*257 + t] = (t < 256) ? xs[t] : 0.f;  // sample 0

  #pragma unroll 1
  for (int s = 0; s < NSTEP; ++s) {
    mv_layer<512, 256>(W0, bf, xs,   act1, bA, gA, beA, red, t, lane, wv, g, ks);
    mv_layer<512, 512>(W1, bf, act1, act2, bB, gB, beB, red, t, lane, wv, g, ks);
    mv_layer<256, 512>(W2, bf, act2, fC,   bC, gC, beC, red, t, lane, wv, g, ks);

    // ---- Euler step + flq --------------------------------------------------
    float u2 = 0.f;
    if (t < 256) {
      const float nz  = ldv(noise, ((s*NB) + row)*256 + t, bf);
      const float ysv = xs[t];
      const float fv  = fC[t];
      const float uu  = fv + ysv;        // u = 2*(f+ys); scale folded below
      u2 = uu*uu;
      xs[t] = ysv + fv*DT_ + SIG_*SQDT_*nz;
    }
    float s1 = u2, s2 = 0.f;
    #pragma unroll
    for (int off = 32; off >= 1; off >>= 1) s1 += __shfl_xor(s1, off, 64);
    (void)s2;
    if (lane == 0) red[wv*2] = s1;
    __syncthreads();
    if (t == 0) {
      float tot = 0.f;
      #pragma unroll
      for (int q = 0; q < 8; ++q) tot += red[q*2];
      lacc_s += 2.f*tot*DT_;             // flq*DT = 0.5*sum((2u)^2)*DT
    }
    __syncthreads();
    if (((s + 1) % NSUB) == 0) {
      const int smp = (s + 1)/NSUB;
      if (t < 257) ysw[(row*8 + smp)*257 + t] = (t < 256) ? xs[t] : lacc_s;
    }
  }
}

// ---------------------------------------------------------------------------
// Epilogue: decoder head + output packing (mu | var | logqp)
// ---------------------------------------------------------------------------
__global__ __launch_bounds__(128)
void k_epi(const float* ws, const void* outh,
           const void* outW, const void* outB,
           const void* lvw, const void* lvb,
           void* d_out)
{
  __shared__ __align__(16) float ysl[8*257];
  __shared__ __align__(16) float ow[8*128];
  __shared__ float dout[64];
  __shared__ float om4[4], os4[4], vmv[4], vrs[4], ob[8], lw[4], lb[4];
  const bool bf = (((const unsigned*)lvw)[0] != 0x3F800000u);
  const int row = blockIdx.x, tid = threadIdx.x;
  const float* ysw = ws + YS_OFF + row*(8*257);
  for (int e = tid; e < 8*257; e += 128) ysl[e] = ysw[e];
  for (int e = tid; e < 1024; e += 128)  ow[e]  = ldv(outW, e, bf);
  if (tid < 8) ob[tid] = ldv(outB, tid, bf);
  if (tid < 4) { lw[tid] = ldv(lvw, tid, bf); lb[tid] = ldv(lvb, tid, bf); }
  if (tid < 4) {  // om / os_ from outcome_history
    float s1 = 0.f, s2 = 0.f;
    for (int t = 0; t < NLH; ++t) {
      const float v = ldv(outh, (row*NLH + t)*4 + tid, bf);
      s1 += v; s2 += v*v;
    }
    const float m = s1 / NLH;
    const float var = s2 / NLH - m*m;
    om4[tid] = m;
    os4[tid] = sqrtf(fmaxf(var, 0.f)) + EPS;   // already includes +EPS
  }
  __syncthreads();
  if (tid < 64) {
    const int smp = tid >> 3, o = tid & 7;
    float a = ob[o];
    #pragma unroll
    for (int k = 0; k < 128; ++k) a += ysl[smp*257 + k]*ow[o*128 + k];
    dout[smp*8 + o] = a;
  }
  __syncthreads();
  if (tid < 4) {  // var_o mean/var over the 8 samples
    float s1 = 0.f, s2 = 0.f;
    #pragma unroll
    for (int smp = 0; smp < 8; ++smp) { const float v = dout[smp*8 + 4 + tid]; s1 += v; s2 += v*v; }
    const float m = s1 / 8.f;
    const float var = s2 / 8.f - m*m;
    vmv[tid] = m;
    vrs[tid] = rsqrtf(var + EPS);
  }
  __syncthreads();
  if (tid < 32) {
    const int smp = tid >> 2, j = tid & 3;
    const float mu = dout[smp*8 + j]*os4[j] + om4[j];
    st_out(d_out, (row*8 + smp)*4 + j, mu, bf);
    const float vo = dout[smp*8 + 4 + j];
    const float vr = sigm((vo - vmv[j])*vrs[j]*lw[j] + lb[j]);
    st_out(d_out, 4096 + (row*8 + smp)*4 + j, vr, bf);
  }
  for (int e = tid; e < 129*8; e += 128) {
    const int j = e >> 3, smp = e & 7;
    st_out(d_out, 8192 + (row*129 + j)*8 + smp, ysl[smp*257 + 128 + j], bf);
  }
}

// ---------------------------------------------------------------------------
extern "C" void kernel_launch(void* const* d_in, const int* in_sizes, int n_in,
                              void* d_out, int out_size, void* d_ws, size_t ws_size,
                              hipStream_t stream) {
  (void)in_sizes; (void)n_in; (void)out_size; (void)ws_size;
  float* ws = (float*)d_ws;
  const void* lnvw = d_in[35];

  k_gru_enc<<<256, 384, 0, stream>>>(
      d_in[0], d_in[1], d_in[2],
      d_in[5], d_in[6], d_in[7], d_in[8],
      d_in[9], d_in[10], d_in[11], d_in[12],
      ws, lnvw);
  k_gru_dec<<<256, 384, 0, stream>>>(
      d_in[1], d_in[3],
      d_in[13], d_in[14], d_in[15], d_in[16],
      d_in[17], d_in[18], d_in[19], d_in[20],
      ws, lnvw);
  k_sde<<<128, 512, 0, stream>>>(
      ws,
      d_in[21], d_in[22], d_in[23], d_in[24],
      d_in[25], d_in[26], d_in[27], d_in[28],
      d_in[29], d_in[30], d_in[31], d_in[32],
      d_in[37], lnvw);
  k_epi<<<128, 128, 0, stream>>>(
      (const float*)d_ws, d_in[2],
      d_in[33], d_in[34], d_in[35], d_in[36],
      d_out);
}

// Round 6
// 2967.960 us; speedup vs baseline: 3.1576x; 1.2192x over previous
//
#include <hip/hip_runtime.h>
#include <hip/hip_bf16.h>

// ---------------------------------------------------------------------------
// CFODE: bi-GRU encoder/decoder -> latent SDE (140 Euler steps, 3-layer MLP
// drift with tanh+LayerNorm) -> decoder head.
//
// Round 8: round-7 proved the exchange-free design (WRITE 127MB->1MB, weights
// L2-resident) but left 24 us/step of L2-LATENCY exposure: the unroll-1 batch
// loop serialized ~20 load->FMA->shfl->tanh chains per step. This round
// software-pipelines the weight stream 2-deep (two NAMED register sets, all
// compile-time indices -> no scratch) and preloads the input vector x into
// registers once per layer (kills per-batch LDS reads). VGPRs are free here:
// 1 WG/CU = 2 waves/SIMD up to 256 VGPR; budget ~170, no spill.
// Zero inter-WG communication. GRU + epilogue unchanged (verified).
// ---------------------------------------------------------------------------

#define EPS    1e-5f
#define DT_    0.05f
#define SQDT_  0.22360680997371674f   // sqrt(0.05)
#define SIG_   0.5f

#define NB    128
#define NLH   64
#define NLP   8
#define NSTEP 140
#define NSUB  20

// ws layout (float offsets). Only WSH (GRU hidden) and YS (trajectory) used.
#define WSH_OFF   0           // [128 rows][4 which][128]     = 65536
#define YS_OFF    65536       // [128 rows][8 samples][257]   = 263168
#define SLOT_OFF  504832      // legacy barrier slots (zeroed, unused)

typedef __attribute__((ext_vector_type(8))) unsigned short ushort8;

__device__ __forceinline__ float bf2f(unsigned short u) {
  return __uint_as_float(((unsigned)u) << 16);
}
__device__ __forceinline__ float ldv(const void* p, int i, bool bf) {
  return bf ? bf2f(((const unsigned short*)p)[i]) : ((const float*)p)[i];
}
__device__ __forceinline__ void st_out(void* p, int i, float v, bool bf) {
  if (bf) ((__hip_bfloat16*)p)[i] = __float2bfloat16(v);
  else    ((float*)p)[i] = v;
}
__device__ __forceinline__ float sigm(float x) { return 1.f / (1.f + expf(-x)); }

// ---------------------------------------------------------------------------
// GRU: 384 threads, thread j owns gate-row j (0..127 r, 128..255 z, 256..383 n)
// ---------------------------------------------------------------------------
template<int INSZ, int TSTEPS>
__device__ void gru_run(const float* xs, int rev,
                        const void* Wih, const void* Whh,
                        const void* bih, const void* bhh,
                        bool bf, float* hout,
                        float* h0, float* h1, float* rz)
{
  const int j = threadIdx.x;
  float whh[128];
  float wih[INSZ];
  if (bf) {
    const unsigned short* wp = (const unsigned short*)Whh;
    #pragma unroll
    for (int k = 0; k < 128; ++k) whh[k] = bf2f(wp[j*128 + k]);
    const unsigned short* ip = (const unsigned short*)Wih;
    #pragma unroll
    for (int c = 0; c < INSZ; ++c) wih[c] = bf2f(ip[j*INSZ + c]);
  } else {
    const float* wp = (const float*)Whh;
    #pragma unroll
    for (int k = 0; k < 128; ++k) whh[k] = wp[j*128 + k];
    const float* ip = (const float*)Wih;
    #pragma unroll
    for (int c = 0; c < INSZ; ++c) wih[c] = ip[j*INSZ + c];
  }
  const float bi = ldv(bih, j, bf);
  const float bh = ldv(bhh, j, bf);
  if (j < 128) h0[j] = 0.f;
  __syncthreads();

  #pragma unroll 1
  for (int it = 0; it < TSTEPS; ++it) {
    const float* hc = (it & 1) ? h1 : h0;
    float*       hn = (it & 1) ? h0 : h1;
    const int t = rev ? (TSTEPS - 1 - it) : it;
    float gh = bh;
    const float4* h4 = (const float4*)hc;
    #pragma unroll
    for (int k4 = 0; k4 < 32; ++k4) {
      const float4 hv = h4[k4];
      gh += whh[k4*4+0]*hv.x + whh[k4*4+1]*hv.y + whh[k4*4+2]*hv.z + whh[k4*4+3]*hv.w;
    }
    float gi = bi;
    #pragma unroll
    for (int c = 0; c < INSZ; ++c) gi += wih[c] * xs[t*INSZ + c];
    if (j < 256) rz[j] = sigm(gi + gh);      // r (0..127), z (128..255)
    __syncthreads();
    if (j >= 256) {                           // n-threads also do the h update
      const int i = j - 256;
      const float n = tanhf(gi + rz[i]*gh);   // inn + r*hn (biases kept separate)
      const float z = rz[128 + i];
      hn[i] = (1.f - z)*n + z*hc[i];
    }
    __syncthreads();
  }
  const float* hf = (TSTEPS & 1) ? h1 : h0;
  if (j < 128) hout[j] = hf[j];
}

__global__ __launch_bounds__(384)
void k_gru_enc(const void* cov, const void* trh, const void* outh,
               const void* Wf, const void* Uf, const void* bf_, const void* cf_,
               const void* Wb, const void* Ub, const void* bb_, const void* cb_,
               float* ws, const void* lnvw)
{
  __shared__ __align__(16) float xs[NLH*28];
  __shared__ __align__(16) float h0[128], h1[128];
  __shared__ float rz[256];
  __shared__ float sm_[28], ss_[28];
  const bool bf = (((const unsigned*)lnvw)[0] != 0x3F800000u);
  const int bid = blockIdx.x;
  const int row = bid >> 1, back = bid & 1;
  const int tid = threadIdx.x;

  if (bid == 0) {  // legacy slot zeroing (region unused this round; harmless)
    unsigned* slots = (unsigned*)(ws + SLOT_OFF);
    for (int e = tid; e < 4096; e += 384) slots[e] = 0u;
  }
  if (tid < 28) {  // per-feature mean/std over time (population std)
    const void* src; int w; int f2;
    if (tid < 16)      { src = cov;  w = 16; f2 = tid; }
    else if (tid < 24) { src = trh;  w = 8;  f2 = tid - 16; }
    else               { src = outh; w = 4;  f2 = tid - 24; }
    float s1 = 0.f, s2 = 0.f;
    for (int t = 0; t < NLH; ++t) {
      const float v = ldv(src, (row*NLH + t)*w + f2, bf);
      s1 += v; s2 += v*v;
    }
    const float m = s1 / NLH;
    const float var = s2 / NLH - m*m;
    sm_[tid] = m;
    ss_[tid] = sqrtf(fmaxf(var, 0.f)) + EPS;
  }
  __syncthreads();
  for (int e = tid; e < NLH*28; e += 384) {  // enc_in = [ch(16), th(8), oh(4)]
    const int t = e / 28, f2 = e % 28;
    const void* src; int w; int ff;
    if (f2 < 16)      { src = cov;  w = 16; ff = f2; }
    else if (f2 < 24) { src = trh;  w = 8;  ff = f2 - 16; }
    else              { src = outh; w = 4;  ff = f2 - 24; }
    const float v = ldv(src, (row*NLH + t)*w + ff, bf);
    xs[e] = (v - sm_[f2]) / ss_[f2];
  }
  __syncthreads();
  float* hout = ws + WSH_OFF + (row*4 + back)*128;
  if (back == 0) gru_run<28, NLH>(xs, 0, Wf, Uf, bf_, cf_, bf, hout, h0, h1, rz);
  else           gru_run<28, NLH>(xs, 1, Wb, Ub, bb_, cb_, bf, hout, h0, h1, rz);
}

__global__ __launch_bounds__(384)
void k_gru_dec(const void* trh, const void* trt,
               const void* Wf, const void* Uf, const void* bf_, const void* cf_,
               const void* Wb, const void* Ub, const void* bb_, const void* cb_,
               float* ws, const void* lnvw)
{
  __shared__ __align__(16) float xs[NLP*8];
  __shared__ __align__(16) float h0[128], h1[128];
  __shared__ float rz[256];
  __shared__ float sm_[8], ss_[8];
  const bool bf = (((const unsigned*)lnvw)[0] != 0x3F800000u);
  const int row = blockIdx.x >> 1, back = blockIdx.x & 1;
  const int tid = threadIdx.x;
  if (tid < 8) {  // treatment stats come from treatment_history
    float s1 = 0.f, s2 = 0.f;
    for (int t = 0; t < NLH; ++t) {
      const float v = ldv(trh, (row*NLH + t)*8 + tid, bf);
      s1 += v; s2 += v*v;
    }
    const float m = s1 / NLH;
    const float var = s2 / NLH - m*m;
    sm_[tid] = m;
    ss_[tid] = sqrtf(fmaxf(var, 0.f)) + EPS;
  }
  __syncthreads();
  for (int e = tid; e < NLP*8; e += 384) {
    const int t = e >> 3, f2 = e & 7;
    const float v = ldv(trt, (row*NLP + t)*8 + f2, bf);
    xs[e] = (v - sm_[f2]) / ss_[f2];
  }
  __syncthreads();
  float* hout = ws + WSH_OFF + (row*4 + 2 + back)*128;
  if (back == 0) gru_run<8, NLP>(xs, 0, Wf, Uf, bf_, cf_, bf, hout, h0, h1, rz);
  else           gru_run<8, NLP>(xs, 1, Wb, Ub, bb_, cb_, bf, hout, h0, h1, rz);
}

// ---------------------------------------------------------------------------
// SDE kernel: 1 row per WG, 512 threads (8 waves), weights streamed from L2.
// Lane = (g = lane>>3 row-group, ks = lane&7 k-slot); an 8-lane group owns one
// output row per batch, reading 128B of the row per instruction (coalesced).
// bf16 path is 2-deep software-pipelined: weight batch b+1 is in flight while
// batch b computes; x lives in registers for the whole layer.
// ---------------------------------------------------------------------------
template<int N, int K>
__device__ __forceinline__ void mv_layer_bf(
    const unsigned short* W, const float* in, float* out,
    const float* bias, const float* gamma, const float* beta,
    float* red, int t, int lane, int wv, int g, int ks)
{
  constexpr int RPW = N/8;     // rows per wave
  constexpr int NBT = RPW/8;   // 8-row batches per wave (8,8,4) - even
  constexpr int KI  = K/64;    // 128B chunks per row per thread (4 or 8)

  // x -> registers once per layer (LDS broadcast reads, conflict-free)
  float4 xr[2*KI];
  #pragma unroll
  for (int kt = 0; kt < KI; ++kt) {
    xr[2*kt]   = *(const float4*)(in + kt*64 + ks*8);
    xr[2*kt+1] = *(const float4*)(in + kt*64 + ks*8 + 4);
  }
  const unsigned short* Wb0 = W + (wv*RPW + g)*K + ks*8;
  ushort8 wa[KI], wb[KI];
  #pragma unroll
  for (int kt = 0; kt < KI; ++kt) wa[kt] = *(const ushort8*)(Wb0 + kt*64);

  float ws1 = 0.f, ws2 = 0.f;
  #pragma unroll 1
  for (int b = 0; b < NBT; b += 2) {
    #pragma unroll
    for (int kt = 0; kt < KI; ++kt)        // prefetch batch b+1
      wb[kt] = *(const ushort8*)(Wb0 + (b+1)*8*K + kt*64);
    {                                       // compute batch b (waits wa only)
      float a0 = 0.f, a1 = 0.f;
      #pragma unroll
      for (int kt = 0; kt < KI; ++kt) {
        const ushort8 w8 = wa[kt];
        const float4 xa = xr[2*kt], xb = xr[2*kt+1];
        a0 += bf2f(w8[0])*xa.x + bf2f(w8[1])*xa.y
            + bf2f(w8[2])*xa.z + bf2f(w8[3])*xa.w;
        a1 += bf2f(w8[4])*xb.x + bf2f(w8[5])*xb.y
            + bf2f(w8[6])*xb.z + bf2f(w8[7])*xb.w;
      }
      float acc = a0 + a1;
      acc += __shfl_xor(acc, 1, 64);
      acc += __shfl_xor(acc, 2, 64);
      acc += __shfl_xor(acc, 4, 64);
      const int row = wv*RPW + b*8 + g;
      const float v = tanhf(acc + bias[row]);
      if (ks == 0) { out[row] = v; ws1 += v; ws2 += v*v; }
    }
    if (b + 2 < NBT) {
      #pragma unroll
      for (int kt = 0; kt < KI; ++kt)      // prefetch batch b+2
        wa[kt] = *(const ushort8*)(Wb0 + (b+2)*8*K + kt*64);
    }
    {                                       // compute batch b+1 (waits wb)
      float a0 = 0.f, a1 = 0.f;
      #pragma unroll
      for (int kt = 0; kt < KI; ++kt) {
        const ushort8 w8 = wb[kt];
        const float4 xa = xr[2*kt], xb = xr[2*kt+1];
        a0 += bf2f(w8[0])*xa.x + bf2f(w8[1])*xa.y
            + bf2f(w8[2])*xa.z + bf2f(w8[3])*xa.w;
        a1 += bf2f(w8[4])*xb.x + bf2f(w8[5])*xb.y
            + bf2f(w8[6])*xb.z + bf2f(w8[7])*xb.w;
      }
      float acc = a0 + a1;
      acc += __shfl_xor(acc, 1, 64);
      acc += __shfl_xor(acc, 2, 64);
      acc += __shfl_xor(acc, 4, 64);
      const int row = wv*RPW + (b+1)*8 + g;
      const float v = tanhf(acc + bias[row]);
      if (ks == 0) { out[row] = v; ws1 += v; ws2 += v*v; }
    }
  }
  #pragma unroll
  for (int off = 32; off >= 1; off >>= 1) {  // wave totals (non-ks0 lanes = 0)
    ws1 += __shfl_xor(ws1, off, 64);
    ws2 += __shfl_xor(ws2, off, 64);
  }
  if (lane == 0) { red[wv*2] = ws1; red[wv*2 + 1] = ws2; }
  __syncthreads();
  float t1 = 0.f, t2 = 0.f;
  #pragma unroll
  for (int q = 0; q < 8; ++q) { t1 += red[q*2]; t2 += red[q*2 + 1]; }
  const float m = t1/(float)N, var = t2/(float)N - m*m, rs = rsqrtf(var + EPS);
  if (t < N) out[t] = (out[t] - m)*rs*gamma[t] + beta[t];
  __syncthreads();
}

// f32 fallback: round-7 structure (correctness path; bench runs bf16).
template<int N, int K>
__device__ __forceinline__ void mv_layer_f32(
    const float* W, const float* in, float* out,
    const float* bias, const float* gamma, const float* beta,
    float* red, int t, int lane, int wv, int g, int ks)
{
  constexpr int RPW = N/8;
  constexpr int NBT = RPW/8;
  constexpr int KI  = K/64;
  float ws1 = 0.f, ws2 = 0.f;
  #pragma unroll 1
  for (int b = 0; b < NBT; ++b) {
    const int row = wv*RPW + b*8 + g;
    const float* wr = W + row*K + ks*8;
    float a0 = 0.f, a1 = 0.f;
    #pragma unroll
    for (int kt = 0; kt < KI; ++kt) {
      const float4 w0 = *(const float4*)(wr + kt*64);
      const float4 w1 = *(const float4*)(wr + kt*64 + 4);
      const float4 xa = *(const float4*)(in + kt*64 + ks*8);
      const float4 xb = *(const float4*)(in + kt*64 + ks*8 + 4);
      a0 += w0.x*xa.x + w0.y*xa.y + w0.z*xa.z + w0.w*xa.w;
      a1 += w1.x*xb.x + w1.y*xb.y + w1.z*xb.z + w1.w*xb.w;
    }
    float acc = a0 + a1;
    acc += __shfl_xor(acc, 1, 64);
    acc += __shfl_xor(acc, 2, 64);
    acc += __shfl_xor(acc, 4, 64);
    const float v = tanhf(acc + bias[row]);
    if (ks == 0) { out[row] = v; ws1 += v; ws2 += v*v; }
  }
  #pragma unroll
  for (int off = 32; off >= 1; off >>= 1) {
    ws1 += __shfl_xor(ws1, off, 64);
    ws2 += __shfl_xor(ws2, off, 64);
  }
  if (lane == 0) { red[wv*2] = ws1; red[wv*2 + 1] = ws2; }
  __syncthreads();
  float t1 = 0.f, t2 = 0.f;
  #pragma unroll
  for (int q = 0; q < 8; ++q) { t1 += red[q*2]; t2 += red[q*2 + 1]; }
  const float m = t1/(float)N, var = t2/(float)N - m*m, rs = rsqrtf(var + EPS);
  if (t < N) out[t] = (out[t] - m)*rs*gamma[t] + beta[t];
  __syncthreads();
}

__global__ __launch_bounds__(512)
void k_sde(float* ws,
           const void* W0, const void* b0, const void* g0, const void* be0,
           const void* W1, const void* b1, const void* g1, const void* be1,
           const void* W2, const void* b2, const void* g2, const void* be2,
           const void* noise, const void* lnvw)
{
  __shared__ __align__(16) float xs[256];    // latent state y
  __shared__ __align__(16) float act1[512];  // layer-A out
  __shared__ __align__(16) float act2[512];  // layer-B out
  __shared__ __align__(16) float fC[256];    // layer-C out (drift f)
  __shared__ float prm[3840];                // bA gA beA bB gB beB bC gC beC
  __shared__ float red[16];
  __shared__ float lacc_s;

  const bool bf = (((const unsigned*)lnvw)[0] != 0x3F800000u);
  const int row = blockIdx.x;                // 128 rows, one per WG
  const int t = threadIdx.x;
  const int lane = t & 63, wv = t >> 6;
  const int g = lane >> 3, ks = lane & 7;

  float* bA = prm;        float* gA = prm +  512; float* beA = prm + 1024;
  float* bB = prm + 1536; float* gB = prm + 2048; float* beB = prm + 2560;
  float* bC = prm + 3072; float* gC = prm + 3328; float* beC = prm + 3584;
  bA[t] = ldv(b0, t, bf); gA[t] = ldv(g0, t, bf); beA[t] = ldv(be0, t, bf);
  bB[t] = ldv(b1, t, bf); gB[t] = ldv(g1, t, bf); beB[t] = ldv(be1, t, bf);
  if (t < 256) { bC[t] = ldv(b2, t, bf); gC[t] = ldv(g2, t, bf); beC[t] = ldv(be2, t, bf); }

  // x0 = [0.5*(enc_f+enc_b), 0.5*(dec_f+dec_b)]
  const float* wsh = ws + WSH_OFF;
  if (t < 256) {
    float v;
    if (t < 128) v = 0.5f*(wsh[(row*4 + 0)*128 + t]       + wsh[(row*4 + 1)*128 + t]);
    else         v = 0.5f*(wsh[(row*4 + 2)*128 + (t-128)] + wsh[(row*4 + 3)*128 + (t-128)]);
    xs[t] = v;
  }
  if (t == 0) lacc_s = 0.f;
  __syncthreads();
  float* ysw = ws + YS_OFF;
  if (t < 257) ysw[(row*8 + 0)*257 + t] = (t < 256) ? xs[t] : 0.f;  // sample 0

  #pragma unroll 1
  for (int s = 0; s < NSTEP; ++s) {
    // prefetch this step's noise early; consumed in the Euler phase
    float nzv = 0.f;
    if (t < 256) nzv = ldv(noise, ((s*NB) + row)*256 + t, bf);

    if (bf) {
      mv_layer_bf<512, 256>((const unsigned short*)W0, xs,   act1, bA, gA, beA, red, t, lane, wv, g, ks);
      mv_layer_bf<512, 512>((const unsigned short*)W1, act1, act2, bB, gB, beB, red, t, lane, wv, g, ks);
      mv_layer_bf<256, 512>((const unsigned short*)W2, act2, fC,   bC, gC, beC, red, t, lane, wv, g, ks);
    } else {
      mv_layer_f32<512, 256>((const float*)W0, xs,   act1, bA, gA, beA, red, t, lane, wv, g, ks);
      mv_layer_f32<512, 512>((const float*)W1, act1, act2, bB, gB, beB, red, t, lane, wv, g, ks);
      mv_layer_f32<256, 512>((const float*)W2, act2, fC,   bC, gC, beC, red, t, lane, wv, g, ks);
    }

    // ---- Euler step + flq --------------------------------------------------
    float u2 = 0.f;
    if (t < 256) {
      const float ysv = xs[t];
      const float fv  = fC[t];
      const float uu  = fv + ysv;        // u = 2*(f+ys); scale folded below
      u2 = uu*uu;
      xs[t] = ysv + fv*DT_ + SIG_*SQDT_*nzv;
    }
    float s1 = u2;
    #pragma unroll
    for (int off = 32; off >= 1; off >>= 1) s1 += __shfl_xor(s1, off, 64);
    if (lane == 0) red[wv*2] = s1;
    __syncthreads();
    if (t == 0) {
      float tot = 0.f;
      #pragma unroll
      for (int q = 0; q < 8; ++q) tot += red[q*2];
      lacc_s += 2.f*tot*DT_;             // flq*DT = 0.5*sum((2u)^2)*DT
    }
    __syncthreads();
    if (((s + 1) % NSUB) == 0) {
      const int smp = (s + 1)/NSUB;
      if (t < 257) ysw[(row*8 + smp)*257 + t] = (t < 256) ? xs[t] : lacc_s;
    }
  }
}

// ---------------------------------------------------------------------------
// Epilogue: decoder head + output packing (mu | var | logqp)
// ---------------------------------------------------------------------------
__global__ __launch_bounds__(128)
void k_epi(const float* ws, const void* outh,
           const void* outW, const void* outB,
           const void* lvw, const void* lvb,
           void* d_out)
{
  __shared__ __align__(16) float ysl[8*257];
  __shared__ __align__(16) float ow[8*128];
  __shared__ float dout[64];
  __shared__ float om4[4], os4[4], vmv[4], vrs[4], ob[8], lw[4], lb[4];
  const bool bf = (((const unsigned*)lvw)[0] != 0x3F800000u);
  const int row = blockIdx.x, tid = threadIdx.x;
  const float* ysw = ws + YS_OFF + row*(8*257);
  for (int e = tid; e < 8*257; e += 128) ysl[e] = ysw[e];
  for (int e = tid; e < 1024; e += 128)  ow[e]  = ldv(outW, e, bf);
  if (tid < 8) ob[tid] = ldv(outB, tid, bf);
  if (tid < 4) { lw[tid] = ldv(lvw, tid, bf); lb[tid] = ldv(lvb, tid, bf); }
  if (tid < 4) {  // om / os_ from outcome_history
    float s1 = 0.f, s2 = 0.f;
    for (int t = 0; t < NLH; ++t) {
      const float v = ldv(outh, (row*NLH + t)*4 + tid, bf);
      s1 += v; s2 += v*v;
    }
    const float m = s1 / NLH;
    const float var = s2 / NLH - m*m;
    om4[tid] = m;
    os4[tid] = sqrtf(fmaxf(var, 0.f)) + EPS;   // already includes +EPS
  }
  __syncthreads();
  if (tid < 64) {
    const int smp = tid >> 3, o = tid & 7;
    float a = ob[o];
    #pragma unroll
    for (int k = 0; k < 128; ++k) a += ysl[smp*257 + k]*ow[o*128 + k];
    dout[smp*8 + o] = a;
  }
  __syncthreads();
  if (tid < 4) {  // var_o mean/var over the 8 samples
    float s1 = 0.f, s2 = 0.f;
    #pragma unroll
    for (int smp = 0; smp < 8; ++smp) { const float v = dout[smp*8 + 4 + tid]; s1 += v; s2 += v*v; }
    const float m = s1 / 8.f;
    const float var = s2 / 8.f - m*m;
    vmv[tid] = m;
    vrs[tid] = rsqrtf(var + EPS);
  }
  __syncthreads();
  if (tid < 32) {
    const int smp = tid >> 2, j = tid & 3;
    const float mu = dout[smp*8 + j]*os4[j] + om4[j];
    st_out(d_out, (row*8 + smp)*4 + j, mu, bf);
    const float vo = dout[smp*8 + 4 + j];
    const float vr = sigm((vo - vmv[j])*vrs[j]*lw[j] + lb[j]);
    st_out(d_out, 4096 + (row*8 + smp)*4 + j, vr, bf);
  }
  for (int e = tid; e < 129*8; e += 128) {
    const int j = e >> 3, smp = e & 7;
    st_out(d_out, 8192 + (row*129 + j)*8 + smp, ysl[smp*257 + 128 + j], bf);
  }
}

// ---------------------------------------------------------------------------
extern "C" void kernel_launch(void* const* d_in, const int* in_sizes, int n_in,
                              void* d_out, int out_size, void* d_ws, size_t ws_size,
                              hipStream_t stream) {
  (void)in_sizes; (void)n_in; (void)out_size; (void)ws_size;
  float* ws = (float*)d_ws;
  const void* lnvw = d_in[35];

  k_gru_enc<<<256, 384, 0, stream>>>(
      d_in[0], d_in[1], d_in[2],
      d_in[5], d_in[6], d_in[7], d_in[8],
      d_in[9], d_in[10], d_in[11], d_in[12],
      ws, lnvw);
  k_gru_dec<<<256, 384, 0, stream>>>(
      d_in[1], d_in[3],
      d_in[13], d_in[14], d_in[15], d_in[16],
      d_in[17], d_in[18], d_in[19], d_in[20],
      ws, lnvw);
  k_sde<<<128, 512, 0, stream>>>(
      ws,
      d_in[21], d_in[22], d_in[23], d_in[24],
      d_in[25], d_in[26], d_in[27], d_in[28],
      d_in[29], d_in[30], d_in[31], d_in[32],
      d_in[37], lnvw);
  k_epi<<<128, 128, 0, stream>>>(
      (const float*)d_ws, d_in[2],
      d_in[33], d_in[34], d_in[35], d_in[36],
      d_out);
}